// Round 8
// baseline (538.938 us; speedup 1.0000x reference)
//
#include <hip/hip_runtime.h>
#include <hip/hip_bf16.h>
#include <stdint.h>

#define B_ 16
#define S_ 2048
#define H_ 1024
#define N_ 128
#define M_ (B_*N_)    // 2048
#define K5 5120       // compact: 4 relation slots + Init slot (slot 4)
#define MP 2176       // padded rows: 17 tiles of 128 (class-0 block | class-1 block | pad)

typedef __attribute__((ext_vector_type(8))) short s8vec;   // 8 x bf16 (4 VGPRs)
typedef __attribute__((ext_vector_type(4))) short s4vec;   // 4 x bf16 (2 VGPRs)
typedef __attribute__((ext_vector_type(4))) float f4vec;
typedef __hip_bfloat16 bf16;

// ---------------------------------------------------------------------------
// Kernel 0 (merged sort+meta): one block, 1024 threads, thread t owns rows
// g = 2t, 2t+1 (same batch). Also zeroes the 136 split-K tile counters.
__global__ void k_sortmeta(const int* __restrict__ num_ids, const int* __restrict__ is_resp,
                           const float* __restrict__ numbers,
                           int* __restrict__ sigma, int* __restrict__ newgrp,
                           int* __restrict__ respv, float* __restrict__ denom,
                           int* __restrict__ aperm, int* __restrict__ iperm,
                           int* __restrict__ meta, int* __restrict__ tick) {
    __shared__ float nums_s[2048];
    __shared__ int sig_s[2048];
    __shared__ int s0[1024], s1[1024];
    __shared__ int cnt_s[16];
    int t = threadIdx.x;
    int g0 = 2*t, g1 = 2*t + 1;
    int b = g0 >> 7;
    int i0 = g0 & 127, i1 = g1 & 127;
    float n0 = numbers[g0], n1 = numbers[g1];
    int id0 = num_ids[g0], id1 = num_ids[g1];
    int v0 = (id0 >= 0) ? 1 : 0, v1 = (id1 >= 0) ? 1 : 0;
    int rsp0 = (is_resp[g0] == 1) ? 1 : 0, rsp1 = (is_resp[g1] == 1) ? 1 : 0;
    nums_s[g0] = n0; nums_s[g1] = n1;
    if (t < 16) cnt_s[t] = 0;
    if (t < 136) tick[t] = 0;                 // split-K fixup counters
    aperm[t] = -1; aperm[t + 1024] = -1;
    if (t < MP - 2048) aperm[t + 2048] = -1;
    __syncthreads();
    // rank sort (ties by index)
    const float* nb = nums_s + b*N_;
    int p0 = 0, p1 = 0;
    for (int j = 0; j < N_; ++j) {
        float nj = nb[j];
        p0 += (nj < n0 || (nj == n0 && j < i0)) ? 1 : 0;
        p1 += (nj < n1 || (nj == n1 && j < i1)) ? 1 : 0;
    }
    sig_s[b*N_ + p0] = i0;
    sig_s[b*N_ + p1] = i1;
    atomicAdd(&cnt_s[b], v0 + v1);
    __syncthreads();
    // outputs
    sigma[g0] = sig_s[g0]; sigma[g1] = sig_s[g1];
    {
        int cur = sig_s[g0];
        int prv = (i0 > 0) ? sig_s[g0-1] : 0;
        newgrp[g0] = (i0 == 0 || nb[cur] != nb[prv]) ? 1 : 0;
        cur = sig_s[g1];
        prv = sig_s[g1-1];
        newgrp[g1] = (nb[cur] != nb[prv]) ? 1 : 0;   // i1 >= 1 always
    }
    respv[g0] = rsp0 | (v0 << 1);
    respv[g1] = rsp1 | (v1 << 1);
    if (t < 16) denom[t] = fmaxf((float)(cnt_s[t] - 1), 1.0f);
    // class partition scan over row pairs (c = resp bit)
    int a0 = 1 - rsp0, b0 = 1 - rsp1;
    s0[t] = a0 + b0;
    s1[t] = rsp0 + rsp1;
    __syncthreads();
    for (int off = 1; off < 1024; off <<= 1) {
        int w0 = (t >= off) ? s0[t-off] : 0;
        int w1 = (t >= off) ? s1[t-off] : 0;
        __syncthreads();
        s0[t] += w0; s1[t] += w1;
        __syncthreads();
    }
    int C0 = s0[1023], C1 = s1[1023];
    int P0 = ((C0 + 127) >> 7) << 7;
    int ex0 = s0[t] - (a0 + b0);     // exclusive prefix over pairs
    int ex1 = s1[t] - (rsp0 + rsp1);
    int p_a = (rsp0 == 0) ? ex0 : P0 + ex1;
    int p_b = (rsp1 == 0) ? ex0 + a0 : P0 + ex1 + rsp0;
    aperm[p_a] = g0; iperm[g0] = p_a;
    aperm[p_b] = g1; iperm[g1] = p_b;
    if (t == 0) { meta[0] = P0; meta[1] = C0; meta[2] = C1; }
}

// ---------------------------------------------------------------------------
// Kernel 1 (merged prep): three independent jobs in one launch.
//  bid < 2048          : gather Init -> A slot 4, alpha = sigmoid(Init.w_alpha)
//  2048 <= bid < 6144  : W_r -> Wt[class][slot 0..3] bf16 repack
//  6144 <= bid < 6400  : w_f [k][n] -> slot 4 as [n][k], both class stacks
__global__ void k_prep(const float* __restrict__ word_emb, const int* __restrict__ num_ids,
                       const float* __restrict__ w_alpha, const float* __restrict__ b_alpha,
                       const float* __restrict__ denom, const int* __restrict__ iperm,
                       const float* __restrict__ W_r, const float* __restrict__ w_f,
                       bf16* __restrict__ A, float* __restrict__ ascaled,
                       bf16* __restrict__ Wt) {
    __shared__ float lds[64][65];
    int bid = blockIdx.x;
    int t = threadIdx.x;
    if (bid < 2048) {
        // ---- gather + alpha
        int b = bid >> 7, n = bid & 127;
        int idv = num_ids[b*N_ + n];
        int valid = (idv >= 0) ? 1 : 0;
        int idx = idv < 0 ? 0 : (idv > S_-1 ? S_-1 : idv);
        int pr = iperm[b*N_ + n];
        const float4* row = (const float4*)(word_emb + ((size_t)b*S_ + idx)*H_);
        float4 v = row[t];
        float4 w = ((const float4*)w_alpha)[t];
        float part = v.x*w.x + v.y*w.y + v.z*w.z + v.w*w.w;
        union { s4vec v4; bf16 h[4]; } pk;
        pk.h[0] = __float2bfloat16(v.x);
        pk.h[1] = __float2bfloat16(v.y);
        pk.h[2] = __float2bfloat16(v.z);
        pk.h[3] = __float2bfloat16(v.w);
        *(s4vec*)(A + (size_t)pr*K5 + 4*H_ + t*4) = pk.v4;
#pragma unroll
        for (int off = 32; off > 0; off >>= 1) part += __shfl_down(part, off, 64);
        if ((t & 63) == 0) lds[0][t >> 6] = part;
        __syncthreads();
        if (t == 0) {
            float dot = lds[0][0] + lds[0][1] + lds[0][2] + lds[0][3] + b_alpha[0];
            float al = 1.0f / (1.0f + __expf(-dot));
            ascaled[b*N_ + n] = valid ? (al / denom[b]) : 0.0f;
        }
        return;
    }
    if (bid < 6144) {
        // ---- W_r repack: r = 4*(s>>1) + 2*c + (s&1); 8 elems/thread, 16B store.
        size_t o = ((size_t)(bid - 2048)*256 + t)*8;       // over 2*4*H*H elems
        int cs = (int)(o >> 20);                           // H*H = 2^20
        int c = cs >> 2, s = cs & 3;
        int r = ((s >> 1) << 2) + 2*c + (s & 1);
        size_t off = o & (size_t)(H_*H_ - 1);
        const float4* src = (const float4*)(W_r + (size_t)r*H_*H_ + off);
        float4 v0 = src[0], v1 = src[1];
        union { s8vec v8; bf16 h[8]; } pk;
        pk.h[0] = __float2bfloat16(v0.x); pk.h[1] = __float2bfloat16(v0.y);
        pk.h[2] = __float2bfloat16(v0.z); pk.h[3] = __float2bfloat16(v0.w);
        pk.h[4] = __float2bfloat16(v1.x); pk.h[5] = __float2bfloat16(v1.y);
        pk.h[6] = __float2bfloat16(v1.z); pk.h[7] = __float2bfloat16(v1.w);
        *(s8vec*)(Wt + (size_t)(c*5 + s)*H_*H_ + off) = pk.v8;
        return;
    }
    // ---- w_f transpose into slot 4 of both class stacks.
    int bb = bid - 6144;
    int bi = bb & 15, bj = bb >> 4;
    int ty = t >> 4, tx = t & 15;
#pragma unroll
    for (int i = 0; i < 4; ++i) {
        int r = ty*4 + i;                                    // k index within tile
        float4 v = *(const float4*)(w_f + (size_t)(bi*64 + r)*H_ + bj*64 + tx*4);
        lds[r][tx*4+0] = v.x; lds[r][tx*4+1] = v.y;
        lds[r][tx*4+2] = v.z; lds[r][tx*4+3] = v.w;
    }
    __syncthreads();
    bf16* d0 = Wt + (size_t)4*H_*H_;        // class 0 slot 4
    bf16* d1 = Wt + (size_t)9*H_*H_;        // class 1 slot 4
#pragma unroll
    for (int i = 0; i < 4; ++i) {
        int n = ty*4 + i;
        size_t doff = (size_t)(bj*64 + n)*H_ + bi*64 + tx*4;
        union { s4vec v4; bf16 h[4]; } pk;
#pragma unroll
        for (int j = 0; j < 4; ++j) pk.h[j] = __float2bfloat16(lds[tx*4+j][n]);
        *(s4vec*)(d0 + doff) = pk.v4;
        *(s4vec*)(d1 + doff) = pk.v4;
    }
}

// ---------------------------------------------------------------------------
// Kernel 3: build A slots 0-3 via prefix sums over sorted order. Rolling form;
// partial unroll 8 so independent global loads pipeline.
__global__ void k_build(const float* __restrict__ ascaled, const int* __restrict__ sigma,
                        const int* __restrict__ newgrp, const int* __restrict__ respv,
                        const int* __restrict__ iperm, bf16* __restrict__ A) {
    int b = blockIdx.y;
    int h = blockIdx.x*64 + threadIdx.x;
    __shared__ float as_s[N_];
    __shared__ int sig_s[N_], ng_s[N_], rv_s[N_], pm_s[N_];
    for (int j = threadIdx.x; j < N_; j += 64) {
        as_s[j] = ascaled[b*N_ + j];
        sig_s[j] = sigma[b*N_ + j];
        ng_s[j] = newgrp[b*N_ + j];
        rv_s[j] = respv[b*N_ + j];
        pm_s[j] = iperm[b*N_ + j];
    }
    __syncthreads();
    const bf16* initcol = A + 4*H_ + h;          // + pr*K5
    float tot0 = 0.f, tot1 = 0.f;
#pragma unroll 8
    for (int i2 = 0; i2 < N_; ++i2) {
        float v = as_s[i2] * __bfloat162float(initcol[(size_t)pm_s[i2]*K5]);
        if (rv_s[i2] & 1) tot1 += v; else tot0 += v;
    }
    float cS0=0.f, cS1=0.f, cG0=0.f, cG1=0.f;   // strict prefix + current tie group
#pragma unroll 8
    for (int p = 0; p < N_; ++p) {
        int i2 = sig_s[p];
        if (ng_s[p]) { cS0 += cG0; cS1 += cG1; cG0 = 0.f; cG1 = 0.f; }
        float v = as_s[i2] * __bfloat162float(initcol[(size_t)pm_s[i2]*K5]);
        int resp = rv_s[i2] & 1;
        float vf = (rv_s[i2] >> 1) ? 1.0f : 0.0f;
        float G0 = cS0, G1 = cS1;                    // senders with num_j < num_i
        float L0 = tot0 - G0 - (resp ? 0.f : v);     // num_j >= num_i, j != i
        float L1 = tot1 - G1 - (resp ? v : 0.f);
        bf16* Ar = A + (size_t)pm_s[i2]*K5 + h;
        Ar[0*H_] = __float2bfloat16(L0*vf);
        Ar[1*H_] = __float2bfloat16(L1*vf);
        Ar[2*H_] = __float2bfloat16(G0*vf);
        Ar[3*H_] = __float2bfloat16(G1*vf);
        if (resp) cG1 += v; else cG0 += v;
    }
}

// ---------------------------------------------------------------------------
// Kernel 4: GEMM + fused split-K fixup epilogue.
// 128x128 tile, BK=32, KS=8 -> grid 17x8x8 = 1088 blocks (4.25/CU avg; LDS
// 32 KB allows 5/CU) = m97's proven occupancy regime (874-912 TF). 20 steps
// of the 2-phase schedule per block. XCD swizzle 1088 = 8x136: XCD x runs
// exactly ks=x -> per-XCD working set (A-slice 2.8 MB + B-slice 2.6 MB)
// ~L2-resident. Every block streams its f32 partial to P[ks] (no atomics on
// data), __threadfence (release), ticket = atomicAdd(tile counter). Ticket
// KS-1 block: __threadfence (acquire), sums the other 7 partials (L2/L3),
// adds bias, relu, aperm-scatters to out. No polling -> no deadlock path.
// Swizzle (verified round 0, passed): stage chunk c: row=c>>2, LDS slot c&3,
// global piece p=(c&3)^((c>>4)&3); ds_read slot = q ^ ((r>>2)&3) -> <=2-way
// bank aliasing (free, m136).
#define BM 128
#define BN 128
#define BK 32
#define KS 8
#define KSP (K5/KS)        // 640
#define NSTEP (KSP/BK)     // 20

__global__ __launch_bounds__(256, 4) void k_gemm(const bf16* __restrict__ A,
                                                 const bf16* __restrict__ Wt,
                                                 const int* __restrict__ meta,
                                                 const int* __restrict__ aperm,
                                                 const float* __restrict__ b_f,
                                                 float* __restrict__ P,
                                                 int* __restrict__ tick,
                                                 float* __restrict__ out) {
    __shared__ __align__(16) bf16 As0[BM*BK], As1[BM*BK];   // 8 KB each
    __shared__ __align__(16) bf16 Bs0[BN*BK], Bs1[BN*BK];
    __shared__ int tk_s;
    int tid = threadIdx.x;
    int w = tid >> 6, lane = tid & 63;
    int q = lane >> 4, r = lane & 15;
    int bid = blockIdx.x;
    int wg = (bid & 7)*136 + (bid >> 3);     // 1088 = 8x136 bijective; XCD x -> ks=x
    int mt = wg % 17;
    int rest = wg / 17;                      // 0..63
    int nt = rest & 7, ks = rest >> 3;
    int rowBase = mt * BM, colBase = nt * BN;
    int wm = w >> 1, wn = w & 1;             // wave tile 64x64
    int P0 = meta[0];
    const bf16* Wtc = Wt + ((rowBase >= P0) ? (size_t)5*H_*H_ : 0);
    const int kb = ks * KSP;

    f4vec acc[4][4];
#pragma unroll
    for (int mi = 0; mi < 4; ++mi)
#pragma unroll
        for (int ni = 0; ni < 4; ++ni)
#pragma unroll
            for (int e = 0; e < 4; ++e) acc[mi][ni][e] = 0.0f;

    // 4 global_load_lds per thread per stage (A x2, B x2). 512 chunks of 16B
    // per 128x32 tile; chunk c: row=c>>2, LDS slot c&3 (linear byte c*16),
    // global piece p=(c&3)^((c>>4)&3).
    auto STAGE = [&](bf16* AsB, bf16* BsB, int kin) {
        int slot = kin >> 10, koff = kin & 1023;
        const bf16* Wslot = Wtc + ((size_t)slot << 20);
#pragma unroll
        for (int j = 0; j < 2; ++j) {
            int c = tid + j*256;              // chunk id 0..511
            int row = c >> 2;                 // 0..127
            int p = (c & 3) ^ ((c >> 4) & 3);
            const bf16* ga = A + (size_t)(rowBase + row)*K5 + kin + p*8;
            __builtin_amdgcn_global_load_lds((const __attribute__((address_space(1))) void*)ga,
                (__attribute__((address_space(3))) void*)((char*)AsB + j*4096 + w*1024), 16, 0, 0);
            const bf16* gb = Wslot + ((size_t)(colBase + row) << 10) + koff + p*8;
            __builtin_amdgcn_global_load_lds((const __attribute__((address_space(1))) void*)gb,
                (__attribute__((address_space(3))) void*)((char*)BsB + j*4096 + w*1024), 16, 0, 0);
        }
    };

    auto COMPUTE = [&](const bf16* AsB, const bf16* BsB) {
        const short* Asp = (const short*)AsB;
        const short* Bsp = (const short*)BsB;
        s8vec af[4], bfr[4];
        int sl = (q ^ ((r >> 2) & 3)) << 3;      // piece slot, <=2-way banks
#pragma unroll
        for (int mi = 0; mi < 4; ++mi)
            af[mi] = *(const s8vec*)(Asp + (wm*64 + mi*16 + r)*BK + sl);
#pragma unroll
        for (int ni = 0; ni < 4; ++ni)
            bfr[ni] = *(const s8vec*)(Bsp + (wn*64 + ni*16 + r)*BK + sl);
#pragma unroll
        for (int mi = 0; mi < 4; ++mi)
#pragma unroll
            for (int ni = 0; ni < 4; ++ni)
                acc[mi][ni] = __builtin_amdgcn_mfma_f32_16x16x32_bf16(
                    af[mi], bfr[ni], acc[mi][ni], 0, 0, 0);
    };

    // prologue
    STAGE(As0, Bs0, kb);
    asm volatile("s_waitcnt vmcnt(0)" ::: "memory");
    __builtin_amdgcn_s_barrier();
    __builtin_amdgcn_sched_barrier(0);

    for (int t = 0; t < NSTEP; t += 2) {                 // NSTEP = 20 (even)
        STAGE(As1, Bs1, kb + (t + 1)*BK);
        COMPUTE(As0, Bs0);
        asm volatile("s_waitcnt vmcnt(0)" ::: "memory");
        __builtin_amdgcn_s_barrier();
        __builtin_amdgcn_sched_barrier(0);
        if (t + 2 < NSTEP) STAGE(As0, Bs0, kb + (t + 2)*BK);
        COMPUTE(As1, Bs1);
        asm volatile("s_waitcnt vmcnt(0)" ::: "memory");
        __builtin_amdgcn_s_barrier();
        __builtin_amdgcn_sched_barrier(0);
    }

    // ---- stream partial tile to P[ks] (plain stores, exactly-once coverage)
    float* Pk = P + (size_t)ks*MP*H_;
#pragma unroll
    for (int mi = 0; mi < 4; ++mi) {
#pragma unroll
        for (int ni = 0; ni < 4; ++ni) {
            int cc = colBase + wn*64 + ni*16 + r;
#pragma unroll
            for (int e = 0; e < 4; ++e) {
                int rr = rowBase + wm*64 + mi*16 + q*4 + e;
                Pk[(size_t)rr*H_ + cc] = acc[mi][ni][e];
            }
        }
    }
    // release own stores, then take a ticket (one atomic per block)
    __threadfence();
    __syncthreads();
    if (tid == 0) tk_s = atomicAdd(&tick[mt*8 + nt], 1);
    __syncthreads();
    if (tk_s != KS - 1) return;

    // ---- last-arriving block: acquire, reduce the other 7 partials, epilogue
    __threadfence();
    int og[4][4];
    float bias[4];
#pragma unroll
    for (int mi = 0; mi < 4; ++mi) {
        int rb = rowBase + wm*64 + mi*16 + q*4;
#pragma unroll
        for (int e = 0; e < 4; ++e) og[mi][e] = aperm[rb + e];
    }
#pragma unroll
    for (int ni = 0; ni < 4; ++ni) bias[ni] = b_f[colBase + wn*64 + ni*16 + r];
    for (int s = 0; s < KS; ++s) {
        if (s == ks) continue;
        const float* Ps = P + (size_t)s*MP*H_;
#pragma unroll
        for (int mi = 0; mi < 4; ++mi) {
#pragma unroll
            for (int ni = 0; ni < 4; ++ni) {
                int cc = colBase + wn*64 + ni*16 + r;
#pragma unroll
                for (int e = 0; e < 4; ++e) {
                    int rr = rowBase + wm*64 + mi*16 + q*4 + e;
                    acc[mi][ni][e] += Ps[(size_t)rr*H_ + cc];
                }
            }
        }
    }
#pragma unroll
    for (int mi = 0; mi < 4; ++mi) {
#pragma unroll
        for (int ni = 0; ni < 4; ++ni) {
            int cc = colBase + wn*64 + ni*16 + r;
            if (og[mi][0] >= 0) out[(size_t)og[mi][0]*H_ + cc] = fmaxf(acc[mi][ni][0] + bias[ni], 0.0f);
            if (og[mi][1] >= 0) out[(size_t)og[mi][1]*H_ + cc] = fmaxf(acc[mi][ni][1] + bias[ni], 0.0f);
            if (og[mi][2] >= 0) out[(size_t)og[mi][2]*H_ + cc] = fmaxf(acc[mi][ni][2] + bias[ni], 0.0f);
            if (og[mi][3] >= 0) out[(size_t)og[mi][3]*H_ + cc] = fmaxf(acc[mi][ni][3] + bias[ni], 0.0f);
        }
    }
}

// ---------------------------------------------------------------------------
extern "C" void kernel_launch(void* const* d_in, const int* in_sizes, int n_in,
                              void* d_out, int out_size, void* d_ws, size_t ws_size,
                              hipStream_t stream) {
    (void)in_sizes; (void)n_in; (void)out_size; (void)ws_size;
    const float* word_emb = (const float*)d_in[0];
    const int*   num_ids  = (const int*)d_in[1];
    const int*   is_resp  = (const int*)d_in[2];
    const float* numbers  = (const float*)d_in[3];
    const float* w_alpha  = (const float*)d_in[4];
    const float* b_alpha  = (const float*)d_in[5];
    const float* w_f      = (const float*)d_in[6];
    const float* b_f      = (const float*)d_in[7];
    const float* W_r      = (const float*)d_in[8];
    float* out = (float*)d_out;

    char* ws = (char*)d_ws;
    bf16*  Aws     = (bf16*)(ws);                    // [2176][5120] = 22,282,240 B
    bf16*  Wt      = (bf16*)(ws + 22282240);         // [2][5][1024][1024] = 20,971,520 B
    float* Pbuf    = (float*)(ws + 43253760);        // [8][2176][1024] f32 = 71,303,168 B
    float* ascaled = (float*)(ws + 114556928);
    int*   sigma   = (int*)(ws + 114565120);
    int*   newgrp  = (int*)(ws + 114573312);
    int*   respv   = (int*)(ws + 114581504);
    float* denom   = (float*)(ws + 114589696);
    int*   aperm   = (int*)(ws + 114589760);         // [2176]
    int*   iperm   = (int*)(ws + 114598464);         // [2048]
    int*   meta    = (int*)(ws + 114606656);         // [4]
    int*   tick    = (int*)(ws + 114606720);         // [136]

    k_sortmeta<<<1, 1024, 0, stream>>>(num_ids, is_resp, numbers, sigma, newgrp, respv,
                                       denom, aperm, iperm, meta, tick);
    k_prep  <<<6400, 256, 0, stream>>>(word_emb, num_ids, w_alpha, b_alpha, denom, iperm,
                                       W_r, w_f, Aws, ascaled, Wt);
    k_build <<<dim3(16,16), 64, 0, stream>>>(ascaled, sigma, newgrp, respv, iperm, Aws);
    k_gemm  <<<1088, 256, 0, stream>>>(Aws, Wt, meta, aperm, b_f, Pbuf, tick, out);
}

// Round 9
// 295.831 us; speedup vs baseline: 1.8218x; 1.8218x over previous
//
#include <hip/hip_runtime.h>
#include <hip/hip_bf16.h>
#include <stdint.h>

#define B_ 16
#define S_ 2048
#define H_ 1024
#define N_ 128
#define M_ (B_*N_)    // 2048
#define K5 5120       // compact: 4 relation slots + Init slot (slot 4)
#define MP 2176       // padded rows: 17 tiles of 128 (class-0 block | class-1 block | pad)

typedef __attribute__((ext_vector_type(8))) short s8vec;   // 8 x bf16 (4 VGPRs)
typedef __attribute__((ext_vector_type(4))) short s4vec;   // 4 x bf16 (2 VGPRs)
typedef __attribute__((ext_vector_type(4))) float f4vec;
typedef __hip_bfloat16 bf16;

// ---------------------------------------------------------------------------
// Kernel 0 (merged sort+meta): one block, 1024 threads, thread t owns rows
// g = 2t, 2t+1 (same batch). Per-batch O(N^2) rank sort -> sigma/newgrp/respv/
// denom, then the global class-partition scan (aperm/iperm/meta).
__global__ void k_sortmeta(const int* __restrict__ num_ids, const int* __restrict__ is_resp,
                           const float* __restrict__ numbers,
                           int* __restrict__ sigma, int* __restrict__ newgrp,
                           int* __restrict__ respv, float* __restrict__ denom,
                           int* __restrict__ aperm, int* __restrict__ iperm,
                           int* __restrict__ meta) {
    __shared__ float nums_s[2048];
    __shared__ int sig_s[2048];
    __shared__ int s0[1024], s1[1024];
    __shared__ int cnt_s[16];
    int t = threadIdx.x;
    int g0 = 2*t, g1 = 2*t + 1;
    int b = g0 >> 7;
    int i0 = g0 & 127, i1 = g1 & 127;
    float n0 = numbers[g0], n1 = numbers[g1];
    int id0 = num_ids[g0], id1 = num_ids[g1];
    int v0 = (id0 >= 0) ? 1 : 0, v1 = (id1 >= 0) ? 1 : 0;
    int rsp0 = (is_resp[g0] == 1) ? 1 : 0, rsp1 = (is_resp[g1] == 1) ? 1 : 0;
    nums_s[g0] = n0; nums_s[g1] = n1;
    if (t < 16) cnt_s[t] = 0;
    aperm[t] = -1; aperm[t + 1024] = -1;
    if (t < MP - 2048) aperm[t + 2048] = -1;
    __syncthreads();
    // rank sort (ties by index)
    const float* nb = nums_s + b*N_;
    int p0 = 0, p1 = 0;
    for (int j = 0; j < N_; ++j) {
        float nj = nb[j];
        p0 += (nj < n0 || (nj == n0 && j < i0)) ? 1 : 0;
        p1 += (nj < n1 || (nj == n1 && j < i1)) ? 1 : 0;
    }
    sig_s[b*N_ + p0] = i0;
    sig_s[b*N_ + p1] = i1;
    atomicAdd(&cnt_s[b], v0 + v1);
    __syncthreads();
    // outputs
    sigma[g0] = sig_s[g0]; sigma[g1] = sig_s[g1];
    {
        int cur = sig_s[g0];
        int prv = (i0 > 0) ? sig_s[g0-1] : 0;
        newgrp[g0] = (i0 == 0 || nb[cur] != nb[prv]) ? 1 : 0;
        cur = sig_s[g1];
        prv = sig_s[g1-1];
        newgrp[g1] = (nb[cur] != nb[prv]) ? 1 : 0;   // i1 >= 1 always
    }
    respv[g0] = rsp0 | (v0 << 1);
    respv[g1] = rsp1 | (v1 << 1);
    if (t < 16) denom[t] = fmaxf((float)(cnt_s[t] - 1), 1.0f);
    // class partition scan over row pairs (c = resp bit)
    int a0 = 1 - rsp0, b0 = 1 - rsp1;
    s0[t] = a0 + b0;
    s1[t] = rsp0 + rsp1;
    __syncthreads();
    for (int off = 1; off < 1024; off <<= 1) {
        int w0 = (t >= off) ? s0[t-off] : 0;
        int w1 = (t >= off) ? s1[t-off] : 0;
        __syncthreads();
        s0[t] += w0; s1[t] += w1;
        __syncthreads();
    }
    int C0 = s0[1023], C1 = s1[1023];
    int P0 = ((C0 + 127) >> 7) << 7;
    int ex0 = s0[t] - (a0 + b0);     // exclusive prefix over pairs
    int ex1 = s1[t] - (rsp0 + rsp1);
    int p_a = (rsp0 == 0) ? ex0 : P0 + ex1;
    int p_b = (rsp1 == 0) ? ex0 + a0 : P0 + ex1 + rsp0;
    aperm[p_a] = g0; iperm[g0] = p_a;
    aperm[p_b] = g1; iperm[g1] = p_b;
    if (t == 0) { meta[0] = P0; meta[1] = C0; meta[2] = C1; }
}

// ---------------------------------------------------------------------------
// Kernel 1 (merged prep): three independent jobs in one launch.
//  bid < 2048          : gather Init -> A slot 4, alpha = sigmoid(Init.w_alpha)
//  2048 <= bid < 6144  : W_r -> Wt[class][slot 0..3] bf16 repack
//  6144 <= bid < 6400  : w_f [k][n] -> slot 4 as [n][k], both class stacks
__global__ void k_prep(const float* __restrict__ word_emb, const int* __restrict__ num_ids,
                       const float* __restrict__ w_alpha, const float* __restrict__ b_alpha,
                       const float* __restrict__ denom, const int* __restrict__ iperm,
                       const float* __restrict__ W_r, const float* __restrict__ w_f,
                       bf16* __restrict__ A, float* __restrict__ ascaled,
                       bf16* __restrict__ Wt) {
    __shared__ float lds[64][65];
    int bid = blockIdx.x;
    int t = threadIdx.x;
    if (bid < 2048) {
        // ---- gather + alpha
        int b = bid >> 7, n = bid & 127;
        int idv = num_ids[b*N_ + n];
        int valid = (idv >= 0) ? 1 : 0;
        int idx = idv < 0 ? 0 : (idv > S_-1 ? S_-1 : idv);
        int pr = iperm[b*N_ + n];
        const float4* row = (const float4*)(word_emb + ((size_t)b*S_ + idx)*H_);
        float4 v = row[t];
        float4 w = ((const float4*)w_alpha)[t];
        float part = v.x*w.x + v.y*w.y + v.z*w.z + v.w*w.w;
        union { s4vec v4; bf16 h[4]; } pk;
        pk.h[0] = __float2bfloat16(v.x);
        pk.h[1] = __float2bfloat16(v.y);
        pk.h[2] = __float2bfloat16(v.z);
        pk.h[3] = __float2bfloat16(v.w);
        *(s4vec*)(A + (size_t)pr*K5 + 4*H_ + t*4) = pk.v4;
#pragma unroll
        for (int off = 32; off > 0; off >>= 1) part += __shfl_down(part, off, 64);
        if ((t & 63) == 0) lds[0][t >> 6] = part;
        __syncthreads();
        if (t == 0) {
            float dot = lds[0][0] + lds[0][1] + lds[0][2] + lds[0][3] + b_alpha[0];
            float al = 1.0f / (1.0f + __expf(-dot));
            ascaled[b*N_ + n] = valid ? (al / denom[b]) : 0.0f;
        }
        return;
    }
    if (bid < 6144) {
        // ---- W_r repack: r = 4*(s>>1) + 2*c + (s&1); 8 elems/thread, 16B store.
        size_t o = ((size_t)(bid - 2048)*256 + t)*8;       // over 2*4*H*H elems
        int cs = (int)(o >> 20);                           // H*H = 2^20
        int c = cs >> 2, s = cs & 3;
        int r = ((s >> 1) << 2) + 2*c + (s & 1);
        size_t off = o & (size_t)(H_*H_ - 1);
        const float4* src = (const float4*)(W_r + (size_t)r*H_*H_ + off);
        float4 v0 = src[0], v1 = src[1];
        union { s8vec v8; bf16 h[8]; } pk;
        pk.h[0] = __float2bfloat16(v0.x); pk.h[1] = __float2bfloat16(v0.y);
        pk.h[2] = __float2bfloat16(v0.z); pk.h[3] = __float2bfloat16(v0.w);
        pk.h[4] = __float2bfloat16(v1.x); pk.h[5] = __float2bfloat16(v1.y);
        pk.h[6] = __float2bfloat16(v1.z); pk.h[7] = __float2bfloat16(v1.w);
        *(s8vec*)(Wt + (size_t)(c*5 + s)*H_*H_ + off) = pk.v8;
        return;
    }
    // ---- w_f transpose into slot 4 of both class stacks.
    int bb = bid - 6144;
    int bi = bb & 15, bj = bb >> 4;
    int ty = t >> 4, tx = t & 15;
#pragma unroll
    for (int i = 0; i < 4; ++i) {
        int r = ty*4 + i;                                    // k index within tile
        float4 v = *(const float4*)(w_f + (size_t)(bi*64 + r)*H_ + bj*64 + tx*4);
        lds[r][tx*4+0] = v.x; lds[r][tx*4+1] = v.y;
        lds[r][tx*4+2] = v.z; lds[r][tx*4+3] = v.w;
    }
    __syncthreads();
    bf16* d0 = Wt + (size_t)4*H_*H_;        // class 0 slot 4
    bf16* d1 = Wt + (size_t)9*H_*H_;        // class 1 slot 4
#pragma unroll
    for (int i = 0; i < 4; ++i) {
        int n = ty*4 + i;
        size_t doff = (size_t)(bj*64 + n)*H_ + bi*64 + tx*4;
        union { s4vec v4; bf16 h[4]; } pk;
#pragma unroll
        for (int j = 0; j < 4; ++j) pk.h[j] = __float2bfloat16(lds[tx*4+j][n]);
        *(s4vec*)(d0 + doff) = pk.v4;
        *(s4vec*)(d1 + doff) = pk.v4;
    }
}

// ---------------------------------------------------------------------------
// Kernel 3: build A slots 0-3 via prefix sums over sorted order. Rolling form;
// partial unroll 8 so independent global loads pipeline.
__global__ void k_build(const float* __restrict__ ascaled, const int* __restrict__ sigma,
                        const int* __restrict__ newgrp, const int* __restrict__ respv,
                        const int* __restrict__ iperm, bf16* __restrict__ A) {
    int b = blockIdx.y;
    int h = blockIdx.x*64 + threadIdx.x;
    __shared__ float as_s[N_];
    __shared__ int sig_s[N_], ng_s[N_], rv_s[N_], pm_s[N_];
    for (int j = threadIdx.x; j < N_; j += 64) {
        as_s[j] = ascaled[b*N_ + j];
        sig_s[j] = sigma[b*N_ + j];
        ng_s[j] = newgrp[b*N_ + j];
        rv_s[j] = respv[b*N_ + j];
        pm_s[j] = iperm[b*N_ + j];
    }
    __syncthreads();
    const bf16* initcol = A + 4*H_ + h;          // + pr*K5
    float tot0 = 0.f, tot1 = 0.f;
#pragma unroll 8
    for (int i2 = 0; i2 < N_; ++i2) {
        float v = as_s[i2] * __bfloat162float(initcol[(size_t)pm_s[i2]*K5]);
        if (rv_s[i2] & 1) tot1 += v; else tot0 += v;
    }
    float cS0=0.f, cS1=0.f, cG0=0.f, cG1=0.f;   // strict prefix + current tie group
#pragma unroll 8
    for (int p = 0; p < N_; ++p) {
        int i2 = sig_s[p];
        if (ng_s[p]) { cS0 += cG0; cS1 += cG1; cG0 = 0.f; cG1 = 0.f; }
        float v = as_s[i2] * __bfloat162float(initcol[(size_t)pm_s[i2]*K5]);
        int resp = rv_s[i2] & 1;
        float vf = (rv_s[i2] >> 1) ? 1.0f : 0.0f;
        float G0 = cS0, G1 = cS1;                    // senders with num_j < num_i
        float L0 = tot0 - G0 - (resp ? 0.f : v);     // num_j >= num_i, j != i
        float L1 = tot1 - G1 - (resp ? v : 0.f);
        bf16* Ar = A + (size_t)pm_s[i2]*K5 + h;
        Ar[0*H_] = __float2bfloat16(L0*vf);
        Ar[1*H_] = __float2bfloat16(L1*vf);
        Ar[2*H_] = __float2bfloat16(G0*vf);
        Ar[3*H_] = __float2bfloat16(G1*vf);
        if (resp) cG1 += v; else cG0 += v;
    }
}

// ---------------------------------------------------------------------------
// Kernel 4: GEMM partials (round-7 structure, BK=32 for co-residency).
// BM=BN=128, KS=4 -> grid 17x8x4 = 544 blocks. BK=32 => LDS = 4 x 8 KB =
// 32 KB -> 4 blocks/CU capacity -> ALL 544 blocks co-resident (no straggler
// tail wave; round 7's 64 KB variant capped at 2/CU with a 32-block tail).
// 40 steps of the 2-phase schedule (STAGE next -> COMPUTE cur -> vmcnt(0)+
// s_barrier), static buffers. Partials go to P[ks] with plain coalesced
// stores; NO fences/tickets (round 8's device-scope fence storm: cross-XCD
// visibility forced 71 MB through HBM and serialized -> 345 us. Separate
// k_epi dispatch gets the same reduction for free via the kernel boundary).
// Staging/read swizzle identical to rounds 0/8 (numerics verified twice):
// chunk c: row=c>>2, LDS slot c&3, global piece p=(c&3)^((c>>4)&3);
// ds_read slot = q^((r>>2)&3) -> <=4-way bank aliasing (known, benign).
// XCD swizzle 544 = 8x68.
#define BM 128
#define BN 128
#define BK 32
#define KS 4
#define KSP (K5/KS)        // 1280
#define NSTEP (KSP/BK)     // 40

__global__ __launch_bounds__(256, 4) void k_gemm(const bf16* __restrict__ A,
                                                 const bf16* __restrict__ Wt,
                                                 const int* __restrict__ meta,
                                                 float* __restrict__ P) {
    __shared__ __align__(16) bf16 As0[BM*BK], As1[BM*BK];   // 8 KB each
    __shared__ __align__(16) bf16 Bs0[BN*BK], Bs1[BN*BK];
    int tid = threadIdx.x;
    int w = tid >> 6, lane = tid & 63;
    int q = lane >> 4, r = lane & 15;
    int bid = blockIdx.x;
    int wg = (bid & 7)*68 + (bid >> 3);      // 544 = 8x68 bijective
    int mt = wg % 17;
    int rest = wg / 17;                      // 0..31
    int nt = rest & 7, ks = rest >> 3;
    int rowBase = mt * BM, colBase = nt * BN;
    int wm = w >> 1, wn = w & 1;             // wave tile 64x64
    int P0 = meta[0];
    const bf16* Wtc = Wt + ((rowBase >= P0) ? (size_t)5*H_*H_ : 0);
    const int kb = ks * KSP;

    f4vec acc[4][4];
#pragma unroll
    for (int mi = 0; mi < 4; ++mi)
#pragma unroll
        for (int ni = 0; ni < 4; ++ni)
#pragma unroll
            for (int e = 0; e < 4; ++e) acc[mi][ni][e] = 0.0f;

    // 4 global_load_lds per thread per stage (A x2, B x2). 512 chunks of 16B
    // per 128x32 tile; chunk c: row=c>>2, LDS linear byte c*16, global piece
    // p=(c&3)^((c>>4)&3).
    auto STAGE = [&](bf16* AsB, bf16* BsB, int kin) {
        int slot = kin >> 10, koff = kin & 1023;
        const bf16* Wslot = Wtc + ((size_t)slot << 20);
#pragma unroll
        for (int j = 0; j < 2; ++j) {
            int c = tid + j*256;              // chunk id 0..511
            int row = c >> 2;                 // 0..127
            int p = (c & 3) ^ ((c >> 4) & 3);
            const bf16* ga = A + (size_t)(rowBase + row)*K5 + kin + p*8;
            __builtin_amdgcn_global_load_lds((const __attribute__((address_space(1))) void*)ga,
                (__attribute__((address_space(3))) void*)((char*)AsB + j*4096 + w*1024), 16, 0, 0);
            const bf16* gb = Wslot + ((size_t)(colBase + row) << 10) + koff + p*8;
            __builtin_amdgcn_global_load_lds((const __attribute__((address_space(1))) void*)gb,
                (__attribute__((address_space(3))) void*)((char*)BsB + j*4096 + w*1024), 16, 0, 0);
        }
    };

    auto COMPUTE = [&](const bf16* AsB, const bf16* BsB) {
        const short* Asp = (const short*)AsB;
        const short* Bsp = (const short*)BsB;
        s8vec af[4], bfr[4];
        int sl = (q ^ ((r >> 2) & 3)) << 3;      // piece slot
#pragma unroll
        for (int mi = 0; mi < 4; ++mi)
            af[mi] = *(const s8vec*)(Asp + (wm*64 + mi*16 + r)*BK + sl);
#pragma unroll
        for (int ni = 0; ni < 4; ++ni)
            bfr[ni] = *(const s8vec*)(Bsp + (wn*64 + ni*16 + r)*BK + sl);
#pragma unroll
        for (int mi = 0; mi < 4; ++mi)
#pragma unroll
            for (int ni = 0; ni < 4; ++ni)
                acc[mi][ni] = __builtin_amdgcn_mfma_f32_16x16x32_bf16(
                    af[mi], bfr[ni], acc[mi][ni], 0, 0, 0);
    };

    // prologue
    STAGE(As0, Bs0, kb);
    asm volatile("s_waitcnt vmcnt(0)" ::: "memory");
    __builtin_amdgcn_s_barrier();
    __builtin_amdgcn_sched_barrier(0);

    for (int t = 0; t < NSTEP; t += 2) {                 // NSTEP = 40 (even)
        STAGE(As1, Bs1, kb + (t + 1)*BK);
        COMPUTE(As0, Bs0);
        asm volatile("s_waitcnt vmcnt(0)" ::: "memory");
        __builtin_amdgcn_s_barrier();
        __builtin_amdgcn_sched_barrier(0);
        if (t + 2 < NSTEP) STAGE(As0, Bs0, kb + (t + 2)*BK);
        COMPUTE(As1, Bs1);
        asm volatile("s_waitcnt vmcnt(0)" ::: "memory");
        __builtin_amdgcn_s_barrier();
        __builtin_amdgcn_sched_barrier(0);
    }

    // stream partial tile to P[ks] (f32, plain stores, exactly-once coverage)
    float* Pk = P + (size_t)ks*MP*H_;
#pragma unroll
    for (int mi = 0; mi < 4; ++mi) {
#pragma unroll
        for (int ni = 0; ni < 4; ++ni) {
            int cc = colBase + wn*64 + ni*16 + r;
#pragma unroll
            for (int e = 0; e < 4; ++e) {
                int rr = rowBase + wm*64 + mi*16 + q*4 + e;
                Pk[(size_t)rr*H_ + cc] = acc[mi][ni][e];
            }
        }
    }
}

// ---------------------------------------------------------------------------
// Kernel 5: epilogue. out[row] = relu(sum_ks P[ks][iperm[row]] + b_f).
__global__ void k_epi(const float* __restrict__ P, const int* __restrict__ iperm,
                      const float* __restrict__ b_f, float* __restrict__ out) {
    int row = blockIdx.x;
    int pr = iperm[row];
    int t = threadIdx.x;
    float4 v0 = ((const float4*)(P + ((size_t)0*MP + pr)*H_))[t];
    float4 v1 = ((const float4*)(P + ((size_t)1*MP + pr)*H_))[t];
    float4 v2 = ((const float4*)(P + ((size_t)2*MP + pr)*H_))[t];
    float4 v3 = ((const float4*)(P + ((size_t)3*MP + pr)*H_))[t];
    float4 bv = ((const float4*)b_f)[t];
    float4 o;
    o.x = fmaxf(v0.x + v1.x + v2.x + v3.x + bv.x, 0.0f);
    o.y = fmaxf(v0.y + v1.y + v2.y + v3.y + bv.y, 0.0f);
    o.z = fmaxf(v0.z + v1.z + v2.z + v3.z + bv.z, 0.0f);
    o.w = fmaxf(v0.w + v1.w + v2.w + v3.w + bv.w, 0.0f);
    ((float4*)(out + (size_t)row*H_))[t] = o;
}

// ---------------------------------------------------------------------------
extern "C" void kernel_launch(void* const* d_in, const int* in_sizes, int n_in,
                              void* d_out, int out_size, void* d_ws, size_t ws_size,
                              hipStream_t stream) {
    (void)in_sizes; (void)n_in; (void)out_size; (void)ws_size;
    const float* word_emb = (const float*)d_in[0];
    const int*   num_ids  = (const int*)d_in[1];
    const int*   is_resp  = (const int*)d_in[2];
    const float* numbers  = (const float*)d_in[3];
    const float* w_alpha  = (const float*)d_in[4];
    const float* b_alpha  = (const float*)d_in[5];
    const float* w_f      = (const float*)d_in[6];
    const float* b_f      = (const float*)d_in[7];
    const float* W_r      = (const float*)d_in[8];
    float* out = (float*)d_out;

    char* ws = (char*)d_ws;
    bf16*  Aws     = (bf16*)(ws);                    // [2176][5120] = 22,282,240 B
    bf16*  Wt      = (bf16*)(ws + 22282240);         // [2][5][1024][1024] = 20,971,520 B
    float* Pbuf    = (float*)(ws + 43253760);        // [4][2176][1024] f32 = 35,651,584 B
    float* ascaled = (float*)(ws + 78905344);
    int*   sigma   = (int*)(ws + 78913536);
    int*   newgrp  = (int*)(ws + 78921728);
    int*   respv   = (int*)(ws + 78929920);
    float* denom   = (float*)(ws + 78938112);
    int*   aperm   = (int*)(ws + 78938176);          // [2176]
    int*   iperm   = (int*)(ws + 78946880);          // [2048]
    int*   meta    = (int*)(ws + 78955072);          // [4]

    k_sortmeta<<<1, 1024, 0, stream>>>(num_ids, is_resp, numbers, sigma, newgrp, respv,
                                       denom, aperm, iperm, meta);
    k_prep  <<<6400, 256, 0, stream>>>(word_emb, num_ids, w_alpha, b_alpha, denom, iperm,
                                       W_r, w_f, Aws, ascaled, Wt);
    k_build <<<dim3(16,16), 64, 0, stream>>>(ascaled, sigma, newgrp, respv, iperm, Aws);
    k_gemm  <<<544,  256, 0, stream>>>(Aws, Wt, meta, Pbuf);
    k_epi   <<<2048, 256, 0, stream>>>(Pbuf, iperm, b_f, out);
}